// Round 1
// baseline (158.236 us; speedup 1.0000x reference)
//
#include <hip/hip_runtime.h>

#define BATCH 16384
#define DIM 128

typedef __attribute__((ext_vector_type(8))) short short8;
typedef __attribute__((ext_vector_type(4))) float floatx4;

__device__ __forceinline__ ushort f2bf(float f) {
    union { float f; uint u; } c; c.f = f;
    return (ushort)((c.u + 0x7FFFu + ((c.u >> 16) & 1u)) >> 16);
}

// Fragment-major slot index for a 32-row activation buffer with KT 32-col
// fragment groups: element (m,k) -> 16B slot
//   ((m>>4)*KT + (k>>5))*64 + ((k>>3)&3)*16 + (m&15),  byte offset (k&7)*2.
__device__ __forceinline__ int slot_idx(int KT, int m, int k) {
    return (((m >> 4) * KT + (k >> 5)) << 6) + (((k >> 3) & 3) << 4) + (m & 15);
}

// ---------------------------------------------------------------------------
// Weight convert: fp32 [K][N] -> bf16 fragment-major [frag(nt,kf)][lane].
// One wave per 16x32 fragment; lane(q,r) holds W[k0+q*8+j][n0+r], j=0..7.
// Frag counts: Wu 8x4=32, W1 16x8=128, W2 8x8=64 -> 224 waves = 56 blocks.
// ---------------------------------------------------------------------------
__global__ __launch_bounds__(256) void convert_kernel(
    const float* __restrict__ Wu, const float* __restrict__ W1,
    const float* __restrict__ W2, short8* __restrict__ WF)
{
    const int f    = blockIdx.x * 4 + (threadIdx.x >> 6);
    const int lane = threadIdx.x & 63;
    const int q = lane >> 4, r = lane & 15;
    const float* W; int N, nt, kf, fl; short8* dst;
    if (f < 32)       { W = Wu; N = 128; fl = f;       nt = fl >> 2; kf = fl & 3; dst = WF;         }
    else if (f < 160) { W = W1; N = 256; fl = f - 32;  nt = fl >> 3; kf = fl & 7; dst = WF + 2048;  }
    else              { W = W2; N = 128; fl = f - 160; nt = fl >> 3; kf = fl & 7; dst = WF + 10240; }
    const int n = nt * 16 + r, k0 = kf * 32 + q * 8;
    short8 v;
    #pragma unroll
    for (int j = 0; j < 8; ++j)
        v[j] = (short)f2bf(W[(size_t)(k0 + j) * N + n]);
    dst[fl * 64 + lane] = v;
}

// ---------------------------------------------------------------------------
// Fully fused model: 32 rows/block, 512 blocks, 512 threads (8 waves).
// vs previous version: 2x waves/CU (16 vs 8, i.e. 4/SIMD), cross-compress
// overlapped with user-L1 (VALU vs MFMA pipes), mlp3 fused into mlp2
// epilogue (h2 stays f32; removes sH2 staging + one barrier phase).
// ---------------------------------------------------------------------------
__global__ __launch_bounds__(512) void fused_kernel(
    const int* __restrict__ user_ids, const int* __restrict__ item_ids,
    const float* __restrict__ rec_target,
    const float* __restrict__ user_tbl, const float* __restrict__ item_tbl,
    const float* __restrict__ entity_tbl,
    const float* __restrict__ w_vv, const float* __restrict__ w_ev,
    const float* __restrict__ w_ve, const float* __restrict__ w_ee,
    const float* __restrict__ bias_v, const float* __restrict__ bias_e,
    const short8* __restrict__ WF, const float* __restrict__ bu,
    const float* __restrict__ b1, const float* __restrict__ b2,
    const float* __restrict__ W3, const float* __restrict__ b3,
    float* __restrict__ out)
{
    __shared__ short8 sU0[512];    // user in   [32][128] frag-major (KT=4)
    __shared__ short8 sU1[512];    // user mid  (KT=4)
    __shared__ short8 sHI[1024];   // high      [32][256] (KT=8)
    __shared__ short8 sH1[1024];   // mlp1 out  (KT=8)
    __shared__ float  sP[8][32];   // mlp3 per-wave row partials

    const int r0   = blockIdx.x * 32;
    const int tid  = threadIdx.x;
    const int wave = tid >> 6, lane = tid & 63;
    const int q    = lane >> 4, r = lane & 15;
    const int row  = tid >> 4, l = tid & 15;   // 16 threads per row (staging)

    // ---- P0: issue all gathers + Wu B-frag prefetch, stage user -> sU0 ----
    const int uid = user_ids[r0 + row];
    const int iid = item_ids[r0 + row];
    const float4* up = (const float4*)(user_tbl   + (size_t)uid * DIM + l * 8);
    const float4* ip = (const float4*)(item_tbl   + (size_t)iid * DIM + l * 8);
    const float4* hp = (const float4*)(entity_tbl + (size_t)iid * DIM + l * 8);
    float4 us4[2] = { up[0], up[1] };
    float4 it4[2] = { ip[0], ip[1] };
    float4 hd4[2] = { hp[0], hp[1] };

    short8 bw[4];   // Wu B-frags, nt = wave; shared by user L1 and L2
    #pragma unroll
    for (int kf = 0; kf < 4; ++kf)
        bw[kf] = WF[(wave * 4 + kf) * 64 + lane];

    if (tid < 32) out[BATCH + r0 + tid] = rec_target[r0 + tid];

    {   // row `row`, cols l*8 .. l*8+7 = exactly one 16B slot
        const float* uf = (const float*)us4;
        short8 v;
        #pragma unroll
        for (int j = 0; j < 8; ++j) v[j] = (short)f2bf(uf[j]);
        sU0[slot_idx(4, row, l * 8)] = v;
    }
    __syncthreads();

    // ---- P1: user L1 (sU0 -> sU1, MFMA) || cross-compress (VALU) ----
    {
        short8 a[2][4];
        #pragma unroll
        for (int mt = 0; mt < 2; ++mt)
            #pragma unroll
            for (int kf = 0; kf < 4; ++kf)
                a[mt][kf] = sU0[(mt * 4 + kf) * 64 + lane];
        const int col = wave * 16 + r;     // NT=8, one col-tile per wave
        const float bs = bu[col];
        const int kc = col >> 5, qc = (col >> 3) & 3, e = col & 7;
        ushort* dst = (ushort*)sU1;
        #pragma unroll
        for (int mt = 0; mt < 2; ++mt) {
            floatx4 acc = {0.f, 0.f, 0.f, 0.f};
            #pragma unroll
            for (int kf = 0; kf < 4; ++kf)
                acc = __builtin_amdgcn_mfma_f32_16x16x32_bf16(a[mt][kf], bw[kf], acc, 0, 0, 0);
            #pragma unroll
            for (int rr = 0; rr < 4; ++rr)
                dst[(((mt * 4 + kc) << 6) + (qc << 4) + q * 4 + rr) * 8 + e] =
                    f2bf(fmaxf(acc[rr] + bs, 0.f));
        }
    }
    // cross-compress (2 layers, fp32, in registers) -> sHI cols 128..255
    {
        const float bv = bias_v[0], be = bias_e[0];
        #pragma unroll
        for (int lay = 0; lay < 2; ++lay) {
            float hv = 0.f, iv = 0.f, he = 0.f, ie = 0.f;
            #pragma unroll
            for (int i = 0; i < 2; ++i) {
                float4 wvv = ((const float4*)w_vv)[l * 2 + i];
                float4 wev = ((const float4*)w_ev)[l * 2 + i];
                float4 wve = ((const float4*)w_ve)[l * 2 + i];
                float4 wee = ((const float4*)w_ee)[l * 2 + i];
                hv += hd4[i].x * wvv.x + hd4[i].y * wvv.y + hd4[i].z * wvv.z + hd4[i].w * wvv.w;
                iv += it4[i].x * wev.x + it4[i].y * wev.y + it4[i].z * wev.z + it4[i].w * wev.w;
                he += hd4[i].x * wve.x + hd4[i].y * wve.y + hd4[i].z * wve.z + hd4[i].w * wve.w;
                ie += it4[i].x * wee.x + it4[i].y * wee.y + it4[i].z * wee.z + it4[i].w * wee.w;
            }
            hv += __shfl_xor(hv, 1); hv += __shfl_xor(hv, 2); hv += __shfl_xor(hv, 4); hv += __shfl_xor(hv, 8);
            iv += __shfl_xor(iv, 1); iv += __shfl_xor(iv, 2); iv += __shfl_xor(iv, 4); iv += __shfl_xor(iv, 8);
            he += __shfl_xor(he, 1); he += __shfl_xor(he, 2); he += __shfl_xor(he, 4); he += __shfl_xor(he, 8);
            ie += __shfl_xor(ie, 1); ie += __shfl_xor(ie, 2); ie += __shfl_xor(ie, 4); ie += __shfl_xor(ie, 8);
            #pragma unroll
            for (int i = 0; i < 2; ++i) {
                float4 t = it4[i], h = hd4[i];
                it4[i].x = t.x * hv + h.x * iv + bv;  hd4[i].x = t.x * he + h.x * ie + be;
                it4[i].y = t.y * hv + h.y * iv + bv;  hd4[i].y = t.y * he + h.y * ie + be;
                it4[i].z = t.z * hv + h.z * iv + bv;  hd4[i].z = t.z * he + h.z * ie + be;
                it4[i].w = t.w * hv + h.w * iv + bv;  hd4[i].w = t.w * he + h.w * ie + be;
            }
        }
        const float* itf = (const float*)it4;
        short8 v;
        #pragma unroll
        for (int j = 0; j < 8; ++j) v[j] = (short)f2bf(itf[j]);
        sHI[slot_idx(8, row, 128 + l * 8)] = v;
    }
    __syncthreads();

    // ---- P2: user L2 (sU1 -> sHI cols 0..127, DKT=8), same bw ----
    {
        short8 a[2][4];
        #pragma unroll
        for (int mt = 0; mt < 2; ++mt)
            #pragma unroll
            for (int kf = 0; kf < 4; ++kf)
                a[mt][kf] = sU1[(mt * 4 + kf) * 64 + lane];
        const int col = wave * 16 + r;
        const float bs = bu[col];
        const int kc = col >> 5, qc = (col >> 3) & 3, e = col & 7;
        ushort* dst = (ushort*)sHI;
        #pragma unroll
        for (int mt = 0; mt < 2; ++mt) {
            floatx4 acc = {0.f, 0.f, 0.f, 0.f};
            #pragma unroll
            for (int kf = 0; kf < 4; ++kf)
                acc = __builtin_amdgcn_mfma_f32_16x16x32_bf16(a[mt][kf], bw[kf], acc, 0, 0, 0);
            #pragma unroll
            for (int rr = 0; rr < 4; ++rr)
                dst[(((mt * 8 + kc) << 6) + (qc << 4) + q * 4 + rr) * 8 + e] =
                    f2bf(fmaxf(acc[rr] + bs, 0.f));
        }
    }
    __syncthreads();

    // ---- P3: mlp1 (sHI x W1 -> sH1), NT=16: nt = wave, wave+8 ----
    {
        const short8* WF1 = WF + 2048;
        ushort* dst = (ushort*)sH1;
        #pragma unroll
        for (int mt = 0; mt < 2; ++mt) {    // mt outer: caps live regs a[8]+b[8]
            short8 a[8];
            #pragma unroll
            for (int kf = 0; kf < 8; ++kf)
                a[kf] = sHI[(mt * 8 + kf) * 64 + lane];
            #pragma unroll
            for (int i = 0; i < 2; ++i) {
                const int nt = wave + i * 8;
                short8 b[8];
                #pragma unroll
                for (int kf = 0; kf < 8; ++kf)
                    b[kf] = WF1[(nt * 8 + kf) * 64 + lane];
                const int col = nt * 16 + r;
                const float bs = b1[col];
                const int kc = col >> 5, qc = (col >> 3) & 3, e = col & 7;
                floatx4 acc = {0.f, 0.f, 0.f, 0.f};
                #pragma unroll
                for (int kf = 0; kf < 8; ++kf)
                    acc = __builtin_amdgcn_mfma_f32_16x16x32_bf16(a[kf], b[kf], acc, 0, 0, 0);
                #pragma unroll
                for (int rr = 0; rr < 4; ++rr)
                    dst[(((mt * 8 + kc) << 6) + (qc << 4) + q * 4 + rr) * 8 + e] =
                        f2bf(fmaxf(acc[rr] + bs, 0.f));
            }
        }
    }
    __syncthreads();

    // ---- P4: mlp2 (sH1 x W2) with mlp3 fused into the epilogue ----
    // h2 stays f32; per-lane h2[row,col]*W3[col], shfl-reduce over the 16
    // col-lanes of this wave's tile, per-wave partials to sP.
    {
        const short8* WF2 = WF + 10240;
        const int col = wave * 16 + r;      // NT=8, one col-tile per wave
        const float bs  = b2[col];
        const float w3c = W3[col];
        short8 b[8];
        #pragma unroll
        for (int kf = 0; kf < 8; ++kf)
            b[kf] = WF2[(wave * 8 + kf) * 64 + lane];
        float v[2][4];
        #pragma unroll
        for (int mt = 0; mt < 2; ++mt) {
            short8 a[8];
            #pragma unroll
            for (int kf = 0; kf < 8; ++kf)
                a[kf] = sH1[(mt * 8 + kf) * 64 + lane];
            floatx4 acc = {0.f, 0.f, 0.f, 0.f};
            #pragma unroll
            for (int kf = 0; kf < 8; ++kf)
                acc = __builtin_amdgcn_mfma_f32_16x16x32_bf16(a[kf], b[kf], acc, 0, 0, 0);
            #pragma unroll
            for (int rr = 0; rr < 4; ++rr)
                v[mt][rr] = fmaxf(acc[rr] + bs, 0.f) * w3c;
        }
        #pragma unroll
        for (int mt = 0; mt < 2; ++mt)
            #pragma unroll
            for (int rr = 0; rr < 4; ++rr) {
                float t = v[mt][rr];
                t += __shfl_xor(t, 1); t += __shfl_xor(t, 2);
                t += __shfl_xor(t, 4); t += __shfl_xor(t, 8);
                v[mt][rr] = t;
            }
        if (r == 0) {
            #pragma unroll
            for (int mt = 0; mt < 2; ++mt)
                #pragma unroll
                for (int rr = 0; rr < 4; ++rr)
                    sP[wave][mt * 16 + q * 4 + rr] = v[mt][rr];
        }
    }
    __syncthreads();

    // ---- P5: final per-row sum over the 8 wave-partials + b3, relu ----
    if (tid < 32) {
        float p = 0.f;
        #pragma unroll
        for (int w = 0; w < 8; ++w) p += sP[w][tid];
        out[r0 + tid] = fmaxf(p + b3[0], 0.f);
    }
}

// ---------------------------------------------------------------------------
extern "C" void kernel_launch(void* const* d_in, const int* in_sizes, int n_in,
                              void* d_out, int out_size, void* d_ws, size_t ws_size,
                              hipStream_t stream)
{
    const int*   user_ids   = (const int*)  d_in[0];
    const int*   item_ids   = (const int*)  d_in[1];
    const float* rec_target = (const float*)d_in[2];
    const float* user_tbl   = (const float*)d_in[3];
    const float* item_tbl   = (const float*)d_in[4];
    const float* entity_tbl = (const float*)d_in[5];
    const float* w_vv       = (const float*)d_in[6];
    const float* w_ev       = (const float*)d_in[7];
    const float* w_ve       = (const float*)d_in[8];
    const float* w_ee       = (const float*)d_in[9];
    const float* bias_v     = (const float*)d_in[10];
    const float* bias_e     = (const float*)d_in[11];
    const float* Wu         = (const float*)d_in[12];
    const float* bu         = (const float*)d_in[13];
    const float* W1         = (const float*)d_in[14];
    const float* b1         = (const float*)d_in[15];
    const float* W2         = (const float*)d_in[16];
    const float* b2         = (const float*)d_in[17];
    const float* W3         = (const float*)d_in[18];
    const float* b3         = (const float*)d_in[19];
    float* out = (float*)d_out;

    short8* WF = (short8*)d_ws;   // Wu frags [0,2048) | W1 [2048,10240) | W2 [10240,14336)

    convert_kernel<<<56, 256, 0, stream>>>(Wu, W1, W2, WF);
    fused_kernel<<<BATCH / 32, 512, 0, stream>>>(
        user_ids, item_ids, rec_target, user_tbl, item_tbl, entity_tbl,
        w_vv, w_ev, w_ve, w_ee, bias_v, bias_e,
        WF, bu, b1, b2, W3, b3, out);
}